// Round 1
// baseline (82.717 us; speedup 1.0000x reference)
//
#include <hip/hip_runtime.h>

// PUMA crossbar conv reduced to exact integer conv (ADC stage is identity:
// max analog column sum 128*3=384 < 2^9-1=511, all integers exact in fp32).
// acc[p,c] = sum_l s16(rne(x*2^12)) * rne(w*2^12); out = clip(rne(acc/2^12))/2^12.

#define CIN 64
#define COUT 128
#define HW 16
#define LDIM 576          // 64*3*3
#define QS 4096.0f

__global__ __launch_bounds__(256) void quant_w_kernel(const float* __restrict__ w,
                                                      int* __restrict__ wq) {
    int tid = blockIdx.x * blockDim.x + threadIdx.x;
    if (tid >= LDIM * COUT) return;
    int c = tid & (COUT - 1);
    int l = tid >> 7;
    // w_net = round(pos*2^12) - round(neg*2^12) = rne(w*2^12) (symmetric RNE,
    // clip at 65535 unreachable for this data distribution).
    wq[tid] = (int)rintf(w[c * LDIM + l] * QS);   // wq layout [l][c]
}

__global__ __launch_bounds__(256) void conv_mvm_kernel(const float* __restrict__ x,
                                                       const int* __restrict__ wq,
                                                       float* __restrict__ out) {
    __shared__ int xq[8][LDIM];   // 18KB: 8 quantized patches
    const int tid = threadIdx.x;
    const int p0 = blockIdx.x * 8;      // 8 consecutive pixels: same b, oh
    const int b  = p0 >> 8;
    const int oh = (p0 >> 4) & 15;
    const int ow0 = p0 & 15;            // 0 or 8

    // stage + quantize 8 im2col patches (zero-pad border), l = cin*9+ki*3+kj
    for (int i = tid; i < 8 * LDIM; i += 256) {
        int px = i / LDIM;
        int l  = i - px * LDIM;
        int cin = l / 9;
        int r   = l - cin * 9;
        int ki  = r / 3;
        int kj  = r - ki * 3;
        int ih = oh - 1 + ki;
        int iw = ow0 + px - 1 + kj;
        float v = 0.0f;
        if (ih >= 0 && ih < HW && iw >= 0 && iw < HW)
            v = x[((b * CIN + cin) * HW + ih) * HW + iw];
        int xi = (int)rintf(v * QS);            // fixed-point, RNE (exact: *2^12 is lossless)
        xq[px][l] = (int)(short)(xi & 0xFFFF);  // 16-bit two's-complement wrap
    }
    __syncthreads();

    const int c  = tid & 127;
    const int ph = tid >> 7;            // pixel half: 0 -> px 0..3, 1 -> px 4..7
    const int* wp = wq + c;
    int acc0 = 0, acc1 = 0, acc2 = 0, acc3 = 0;
    #pragma unroll 2
    for (int l = 0; l < LDIM; l += 4) {
        int4 x0 = *(const int4*)&xq[ph * 4 + 0][l];   // LDS broadcast reads
        int4 x1 = *(const int4*)&xq[ph * 4 + 1][l];
        int4 x2 = *(const int4*)&xq[ph * 4 + 2][l];
        int4 x3 = *(const int4*)&xq[ph * 4 + 3][l];
        int w0 = wp[(l + 0) << 7];                    // coalesced: lane = c
        int w1 = wp[(l + 1) << 7];
        int w2 = wp[(l + 2) << 7];
        int w3 = wp[(l + 3) << 7];
        acc0 += x0.x * w0 + x0.y * w1 + x0.z * w2 + x0.w * w3;
        acc1 += x1.x * w0 + x1.y * w1 + x1.z * w2 + x1.w * w3;
        acc2 += x2.x * w0 + x2.y * w1 + x2.z * w2 + x2.w * w3;
        acc3 += x3.x * w0 + x3.y * w1 + x3.z * w2 + x3.w * w3;
    }

    // accumulator fixed-point quantization: RNE(acc/4096), clip to s16, /4096
    int accs[4] = {acc0, acc1, acc2, acc3};
    #pragma unroll
    for (int j = 0; j < 4; ++j) {
        int a = accs[j];
        int f = a >> 12;                 // floor div 4096
        int r = a & 4095;
        int q = f + ((r > 2048) || (r == 2048 && (f & 1)));  // round-half-even
        q = min(max(q, -32768), 32767);
        int p  = p0 + ph * 4 + j;
        int ow = p & 15;
        out[((b * COUT + c) * HW + oh) * HW + ow] = (float)q * (1.0f / QS);
    }
}

extern "C" void kernel_launch(void* const* d_in, const int* in_sizes, int n_in,
                              void* d_out, int out_size, void* d_ws, size_t ws_size,
                              hipStream_t stream) {
    const float* x = (const float*)d_in[0];   // [4,64,16,16]
    const float* w = (const float*)d_in[1];   // [128,64,3,3]
    float* out = (float*)d_out;               // [4,128,16,16]
    int* wq = (int*)d_ws;                     // 576*128*4 = 294912 B

    quant_w_kernel<<<(LDIM * COUT + 255) / 256, 256, 0, stream>>>(w, wq);
    conv_mvm_kernel<<<1024 / 8, 256, 0, stream>>>(x, wq, out);
}

// Round 2
// 63.269 us; speedup vs baseline: 1.3074x; 1.3074x over previous
//
#include <hip/hip_runtime.h>

// PUMA crossbar conv reduced to exact integer conv (ADC stage is identity:
// max analog column sum 128*3=384 < 2^9-1=511, all integers exact in fp32).
// acc[p,c] = sum_l s16(rne(x*2^12)) * rne(w*2^12); out = clip(rne(acc/2^12))/2^12.
// Both operands fit int16 -> pack 2 l per dword, v_dot2_i32_i16 inner product.

#define CIN 64
#define COUT 128
#define HW 16
#define LDIM 576           // 64*3*3
#define LP (LDIM / 2)      // 288 packed l-pairs
#define NPIX 1024          // 4*16*16 output pixels
#define QS 4096.0f

typedef short short2v __attribute__((ext_vector_type(2)));

__device__ inline int dot2(int a, int b, int c) {
#if __has_builtin(__builtin_amdgcn_sdot2)
    union { int i; short2v v; } ua, ub;
    ua.i = a; ub.i = b;
    return __builtin_amdgcn_sdot2(ua.v, ub.v, c, false);
#else
    return c + (int)(short)(a & 0xFFFF) * (int)(short)(b & 0xFFFF)
             + (a >> 16) * (b >> 16);
#endif
}

// Fused prep: im2col+quantize x -> xq2[p][LP] (packed s16 pairs, LSB l first),
// and quantize w -> wq2[lp][c] (packed s16 pairs). Integer-exact (RNE, s16 wrap).
__global__ __launch_bounds__(256) void prep_kernel(const float* __restrict__ x,
                                                   const float* __restrict__ w,
                                                   int* __restrict__ wq2,
                                                   int* __restrict__ xq2) {
    int tid = blockIdx.x * 256 + threadIdx.x;
    if (tid < NPIX * LP) {
        int p = tid / LP, lp = tid - p * LP;
        int b = p >> 8, oh = (p >> 4) & 15, ow = p & 15;
        int s[2];
#pragma unroll
        for (int j = 0; j < 2; ++j) {
            int l = lp * 2 + j;
            int cin = l / 9, r = l - cin * 9, ki = r / 3, kj = r - ki * 3;
            int ih = oh - 1 + ki, iw = ow - 1 + kj;
            float v = 0.0f;
            if ((unsigned)ih < HW && (unsigned)iw < HW)
                v = x[((b * CIN + cin) * HW + ih) * HW + iw];
            s[j] = (int)rintf(v * QS);          // RNE; exact (x*2^12 lossless)
        }
        xq2[tid] = (int)(((unsigned)(unsigned short)(short)s[1] << 16) |
                         (unsigned short)(short)s[0]);   // s16 two's-c wrap
    } else {
        int j = tid - NPIX * LP;
        if (j < COUT * LP) {
            int c = j / LP, lp = j - c * LP;           // coalesced w reads per c-row
            int s0 = (int)rintf(w[c * LDIM + lp * 2 + 0] * QS);
            int s1 = (int)rintf(w[c * LDIM + lp * 2 + 1] * QS);
            wq2[lp * COUT + c] = (int)(((unsigned)(unsigned short)(short)s1 << 16) |
                                       (unsigned short)(short)s0);
        }
    }
}

// 256 blocks x 256 threads: block = 4 pixels x 128 cout; thread = 2 px x 1 c.
// x staged in LDS (4.6KB, broadcast b128 reads); w streamed coalesced from L2.
__global__ __launch_bounds__(256) void conv_kernel(const int* __restrict__ xq2,
                                                   const int* __restrict__ wq2,
                                                   float* __restrict__ out) {
    __shared__ int4 xs[4][LP / 4];          // 4 px x 288 dwords
    const int tid = threadIdx.x;
    const int p0 = blockIdx.x * 4;
    const int b = p0 >> 8, oh = (p0 >> 4) & 15, ow0 = p0 & 15;

    const int4* src = (const int4*)(xq2 + p0 * LP);   // 16B-aligned (p0%4==0)
    for (int i = tid; i < 4 * LP / 4; i += 256)
        ((int4*)xs)[i] = src[i];
    __syncthreads();

    const int c = tid & 127, h = tid >> 7;
    const int4* xA = xs[2 * h];
    const int4* xB = xs[2 * h + 1];
    int acc0 = 0, acc1 = 0;
#pragma unroll 8
    for (int q = 0; q < LP / 4; ++q) {
        int4 xa = xA[q], xb = xB[q];                  // LDS broadcast
        int w0 = wq2[(q * 4 + 0) * COUT + c];         // coalesced: lane = c
        int w1 = wq2[(q * 4 + 1) * COUT + c];
        int w2 = wq2[(q * 4 + 2) * COUT + c];
        int w3 = wq2[(q * 4 + 3) * COUT + c];
        acc0 = dot2(xa.x, w0, dot2(xa.y, w1, dot2(xa.z, w2, dot2(xa.w, w3, acc0))));
        acc1 = dot2(xb.x, w0, dot2(xb.y, w1, dot2(xb.z, w2, dot2(xb.w, w3, acc1))));
    }

    // accumulator fixed-point quantization: RNE(acc/4096), clip s16, /4096
    int accs[2] = {acc0, acc1};
#pragma unroll
    for (int j = 0; j < 2; ++j) {
        int a = accs[j];
        int f = a >> 12, r = a & 4095;
        int q = f + ((r > 2048) || (r == 2048 && (f & 1)));
        q = min(max(q, -32768), 32767);
        int ow = ow0 + 2 * h + j;
        out[((b * COUT + c) * HW + oh) * HW + ow] = (float)q * (1.0f / QS);
    }
}

extern "C" void kernel_launch(void* const* d_in, const int* in_sizes, int n_in,
                              void* d_out, int out_size, void* d_ws, size_t ws_size,
                              hipStream_t stream) {
    const float* x = (const float*)d_in[0];   // [4,64,16,16]
    const float* w = (const float*)d_in[1];   // [128,64,3,3]
    float* out = (float*)d_out;               // [4,128,16,16]
    int* wq2 = (int*)d_ws;                                  // 288*128*4 = 147456 B
    int* xq2 = (int*)((char*)d_ws + LP * COUT * sizeof(int)); // 1024*288*4 = 1.18 MB

    int prep_jobs = NPIX * LP + COUT * LP;    // 294912 + 36864 = 331776
    prep_kernel<<<prep_jobs / 256, 256, 0, stream>>>(x, w, wq2, xq2);
    conv_kernel<<<NPIX / 4, 256, 0, stream>>>(xq2, wq2, out);
}